// Round 1
// baseline (181.011 us; speedup 1.0000x reference)
//
#include <hip/hip_runtime.h>

#define CC 64
#define HH 128
#define WW 128
#define OO 576   // C * K * K

typedef __attribute__((ext_vector_type(8))) short short8;
typedef __attribute__((ext_vector_type(4))) float floatx4;

__device__ __forceinline__ unsigned short f2bf(float f) {
    unsigned u = __float_as_uint(f);
    u = (u + 0x7FFFu + ((u >> 16) & 1u)) >> 16;   // RTNE
    return (unsigned short)u;
}

// Pre-convert W_gen (576x64 fp32) -> bf16 in workspace
__global__ void ACDA_wconv_kernel(const float* __restrict__ Wg,
                                  unsigned short* __restrict__ Wb) {
    int i = blockIdx.x * 256 + threadIdx.x;
    if (i < OO * CC) Wb[i] = f2bf(Wg[i]);
}

// Fused: per-pixel 1x1-conv filter generation (bf16 MFMA, fp32 acc) + relu +
// 3x3 dynamic depthwise combine. One block = 1 batch x 1 row x 64-px segment.
__global__ __launch_bounds__(256) void ACDA_main_kernel(
    const float* __restrict__ x, const unsigned short* __restrict__ Wb,
    const float* __restrict__ bg, float* __restrict__ out)
{
    __shared__ float bias_s[OO];
    __shared__ float Fbuf[4][2][16][68];   // [wave][dbuf][o_rel][pixel(+4 pad)]

    const int tid  = threadIdx.x;
    const int wave = tid >> 6;
    const int lane = tid & 63;
    const int quad = lane >> 4;
    const int l16  = lane & 15;

    const int bid = blockIdx.x;
    const int seg = bid & 1;
    const int h   = (bid >> 1) & 127;
    const int b   = bid >> 8;
    const int w0  = seg << 6;

    for (int i = tid; i < OO; i += 256) bias_s[i] = bg[i];

    const float* xb = x + (size_t)b * CC * HH * WW;

    // ---- B fragments (X tile, bf16) held in registers for all 9 chunks ----
    // B[k][n]: n = lane&15 (pixel), k = quad*8 + j (channel)
    short8 bfrag[4][2];
#pragma unroll
    for (int nt = 0; nt < 4; ++nt) {
#pragma unroll
        for (int ks = 0; ks < 2; ++ks) {
            short8 v;
#pragma unroll
            for (int j = 0; j < 8; ++j) {
                int c = ks * 32 + quad * 8 + j;
                int w = w0 + nt * 16 + l16;
                v[j] = (short)f2bf(xb[(c * HH + h) * WW + w]);
            }
            bfrag[nt][ks] = v;
        }
    }

    // ---- combine-phase per-lane precompute (clamped cols/rows + kill masks) ----
    int wA = w0 + lane - 1; bool badA = (wA < 0);   if (badA) wA = 0;
    int wB = w0 + lane;
    int wC = w0 + lane + 1; bool badC = (wC > 127); if (badC) wC = 127;
    int rt[3]; bool rbad[3];
#pragma unroll
    for (int di = 0; di < 3; ++di) {
        int rr = h + di - 1;
        rbad[di] = (rr < 0) || (rr > 127);
        rr = rr < 0 ? 0 : (rr > 127 ? 127 : rr);
        rt[di] = rr * WW;
    }
    const int wsel[3]  = {wA, wB, wC};
    const bool wbad[3] = {badA, false, badC};
    const int soffC = wave * 16 * (HH * WW);
    int  pb[3][3]; bool bad[3][3];
#pragma unroll
    for (int di = 0; di < 3; ++di)
#pragma unroll
        for (int dj = 0; dj < 3; ++dj) {
            pb[di][dj]  = soffC + rt[di] + wsel[dj];
            bad[di][dj] = rbad[di] || wbad[dj];
        }

    float oacc[16];
#pragma unroll
    for (int i = 0; i < 16; ++i) oacc[i] = 0.f;

    // ---- 9 m-chunks of 16 filter rows each (wave w owns o in [144w,144w+144)) ----
#pragma unroll
    for (int t = 0; t < 9; ++t) {
        const int obase = wave * 144 + t * 16;
        // A[m][k]: m = lane&15 (filter row), k = quad*8 + j
        const unsigned short* wrow = Wb + (obase + l16) * CC + quad * 8;
        short8 a0 = *(const short8*)(wrow);
        short8 a1 = *(const short8*)(wrow + 32);
        floatx4 acc[4];
#pragma unroll
        for (int nt = 0; nt < 4; ++nt) {
            floatx4 z = {0.f, 0.f, 0.f, 0.f};
            z = __builtin_amdgcn_mfma_f32_16x16x32_bf16(a0, bfrag[nt][0], z, 0, 0, 0);
            z = __builtin_amdgcn_mfma_f32_16x16x32_bf16(a1, bfrag[nt][1], z, 0, 0, 0);
            acc[nt] = z;
        }
        // C[m][n]: n(col) = lane&15, m(row) = quad*4 + reg
#pragma unroll
        for (int nt = 0; nt < 4; ++nt)
#pragma unroll
            for (int reg = 0; reg < 4; ++reg)
                Fbuf[wave][t & 1][quad * 4 + reg][nt * 16 + l16] = acc[nt][reg];
        __syncthreads();

        // combine: each lane = one pixel (p = lane), 16 channels
#pragma unroll
        for (int r = 0; r < 16; ++r) {
            const int idx   = t * 16 + r;       // all compile-time constants
            const int c_rel = idx / 9;
            const int kk    = idx - 9 * c_rel;
            const int di    = kk / 3;
            const int dj    = kk - 3 * di;
            float fv = Fbuf[wave][t & 1][r][lane] + bias_s[obase + r];
            fv = fmaxf(fv, 0.f);
            float pv = xb[pb[di][dj] + c_rel * (HH * WW)];
            if (bad[di][dj]) pv = 0.f;
            oacc[c_rel] = fmaf(fv, pv, oacc[c_rel]);
        }
    }

    float* ob = out + (size_t)b * CC * HH * WW + h * WW + w0 + lane;
#pragma unroll
    for (int i = 0; i < 16; ++i)
        ob[(wave * 16 + i) * (HH * WW)] = oacc[i];
}

extern "C" void kernel_launch(void* const* d_in, const int* in_sizes, int n_in,
                              void* d_out, int out_size, void* d_ws, size_t ws_size,
                              hipStream_t stream) {
    const float* x  = (const float*)d_in[0];
    const float* Wg = (const float*)d_in[1];
    const float* bg = (const float*)d_in[2];
    float* out = (float*)d_out;
    unsigned short* Wb = (unsigned short*)d_ws;   // 576*64*2 = 73728 B

    ACDA_wconv_kernel<<<dim3((OO * CC + 255) / 256), dim3(256), 0, stream>>>(Wg, Wb);
    ACDA_main_kernel<<<dim3(8 * 128 * 2), dim3(256), 0, stream>>>(x, Wb, bg, out);
}

// Round 2
// 120.344 us; speedup vs baseline: 1.5041x; 1.5041x over previous
//
#include <hip/hip_runtime.h>
#include <hip/hip_bf16.h>

#define CC 64
#define HH 128
#define WW 128
#define OO 576   // C * K * K
#define HW (HH * WW)

typedef __attribute__((ext_vector_type(8))) short short8;
typedef __attribute__((ext_vector_type(4))) float floatx4;

__device__ __forceinline__ unsigned short f2bf(float f) {
    unsigned u = __float_as_uint(f);
    u = (u + 0x7FFFu + ((u >> 16) & 1u)) >> 16;   // RTNE
    return (unsigned short)u;
}

// Pre-convert W_gen (576x64 fp32) -> bf16 in workspace
__global__ void ACDA_wconv_kernel(const float* __restrict__ Wg,
                                  unsigned short* __restrict__ Wb) {
    int i = blockIdx.x * 256 + threadIdx.x;
    if (i < OO * CC) Wb[i] = f2bf(Wg[i]);
}

// One block = ONE wave (64 threads): 16 output channels x 64-pixel segment.
// Single-wave workgroup => s_barrier elided by the compiler; LDS ordering is
// guaranteed by in-order DS execution within a wave. No barrier drains.
__global__ __launch_bounds__(64) void ACDA_main_kernel(
    const float* __restrict__ x, const unsigned short* __restrict__ Wb,
    const float* __restrict__ bg, float* __restrict__ out)
{
    __shared__ float Fbuf[16][68];   // +4 pad; 4.4 KB -> occupancy not LDS-capped

    const int lane = threadIdx.x;    // 0..63
    const int quad = lane >> 4;
    const int l16  = lane & 15;

    const int bid = blockIdx.x;      // 8 * 128 * 2 * 4 = 8192 blocks
    const int wv  = bid & 3;         // which 16-channel group
    const int seg = (bid >> 2) & 1;
    const int h   = (bid >> 3) & 127;
    const int b   = bid >> 10;
    const int w0  = seg << 6;

    const float* xb = x + (size_t)b * CC * HW;

    // ---- B fragments (X tile, bf16) held in registers for all 9 chunks ----
    // B[k][n]: n = lane&15 (pixel), k = quad*8 + j (channel)
    short8 bfrag[4][2];
#pragma unroll
    for (int nt = 0; nt < 4; ++nt) {
#pragma unroll
        for (int ks = 0; ks < 2; ++ks) {
            short8 v;
            const int w = w0 + nt * 16 + l16;
#pragma unroll
            for (int j = 0; j < 8; j += 2) {
                const int c = ks * 32 + quad * 8 + j;
                float f0 = xb[(c * HH + h) * WW + w];
                float f1 = xb[((c + 1) * HH + h) * WW + w];
                __hip_bfloat162 p = __float22bfloat162_rn(make_float2(f0, f1));
                unsigned u;
                __builtin_memcpy(&u, &p, 4);
                v[j]     = (short)(u & 0xffffu);
                v[j + 1] = (short)(u >> 16);
            }
            bfrag[nt][ks] = v;
        }
    }

    // ---- combine-phase per-lane precompute (clamped cols/rows + kill masks) ----
    int wA = w0 + lane - 1; bool badA = (wA < 0);   if (badA) wA = 0;
    int wB = w0 + lane;
    int wC = w0 + lane + 1; bool badC = (wC > 127); if (badC) wC = 127;
    int rt[3]; bool rbad[3];
#pragma unroll
    for (int di = 0; di < 3; ++di) {
        int rr = h + di - 1;
        rbad[di] = (rr < 0) || (rr > 127);
        rr = rr < 0 ? 0 : (rr > 127 ? 127 : rr);
        rt[di] = rr * WW;
    }
    const int wsel[3]  = {wA, wB, wC};
    const bool wbad[3] = {badA, false, badC};
    const int soffC = wv * 16 * HW;   // channel-group base for patch loads
    int  pb[3][3]; bool bad[3][3];
#pragma unroll
    for (int di = 0; di < 3; ++di)
#pragma unroll
        for (int dj = 0; dj < 3; ++dj) {
            pb[di][dj]  = soffC + rt[di] + wsel[dj];
            bad[di][dj] = rbad[di] || wbad[dj];
        }

    float oacc[16];
#pragma unroll
    for (int i = 0; i < 16; ++i) oacc[i] = 0.f;

    // ---- 9 m-chunks of 16 filter rows each (this block owns o in [144wv, +144)) ----
#pragma unroll
    for (int t = 0; t < 9; ++t) {
        const int obase = wv * 144 + t * 16;
        // A[m][k]: m = lane&15 (filter row), k = quad*8 + j
        const unsigned short* wrow = Wb + (obase + l16) * CC + quad * 8;
        short8 a0 = *(const short8*)(wrow);
        short8 a1 = *(const short8*)(wrow + 32);
        floatx4 acc[4];
#pragma unroll
        for (int nt = 0; nt < 4; ++nt) {
            floatx4 z = {0.f, 0.f, 0.f, 0.f};
            z = __builtin_amdgcn_mfma_f32_16x16x32_bf16(a0, bfrag[nt][0], z, 0, 0, 0);
            z = __builtin_amdgcn_mfma_f32_16x16x32_bf16(a1, bfrag[nt][1], z, 0, 0, 0);
            acc[nt] = z;
        }
        // C[m][n]: n(col) = lane&15, m(row) = quad*4 + reg
#pragma unroll
        for (int nt = 0; nt < 4; ++nt)
#pragma unroll
            for (int reg = 0; reg < 4; ++reg)
                Fbuf[quad * 4 + reg][nt * 16 + l16] = acc[nt][reg];

        __syncthreads();   // single-wave block: elided; DS in-order guarantees RAW

        // combine: each lane = one pixel (p = lane), 16 filter rows
#pragma unroll
        for (int r = 0; r < 16; ++r) {
            const int idx   = t * 16 + r;       // all compile-time constants
            const int c_rel = idx / 9;
            const int kk    = idx - 9 * c_rel;
            const int di    = kk / 3;
            const int dj    = kk - 3 * di;
            float fv = Fbuf[r][lane] + bg[obase + r];   // bias: wave-uniform s_load
            fv = fmaxf(fv, 0.f);
            float pv = xb[pb[di][dj] + c_rel * HW];
            if (bad[di][dj]) pv = 0.f;
            oacc[c_rel] = fmaf(fv, pv, oacc[c_rel]);
        }
    }

    float* ob = out + (size_t)b * CC * HW + h * WW + w0 + lane;
#pragma unroll
    for (int i = 0; i < 16; ++i)
        ob[(wv * 16 + i) * HW] = oacc[i];
}

extern "C" void kernel_launch(void* const* d_in, const int* in_sizes, int n_in,
                              void* d_out, int out_size, void* d_ws, size_t ws_size,
                              hipStream_t stream) {
    const float* x  = (const float*)d_in[0];
    const float* Wg = (const float*)d_in[1];
    const float* bg = (const float*)d_in[2];
    float* out = (float*)d_out;
    unsigned short* Wb = (unsigned short*)d_ws;   // 576*64*2 = 73728 B

    ACDA_wconv_kernel<<<dim3((OO * CC + 255) / 256), dim3(256), 0, stream>>>(Wg, Wb);
    ACDA_main_kernel<<<dim3(8 * 128 * 2 * 4), dim3(64), 0, stream>>>(x, Wb, bg, out);
}